// Round 5
// baseline (203.945 us; speedup 1.0000x reference)
//
#include <hip/hip_runtime.h>
#include <stdint.h>

typedef __attribute__((ext_vector_type(4))) float f32x4;
typedef __attribute__((ext_vector_type(8))) short bf16x8;
typedef __attribute__((ext_vector_type(4))) unsigned short u16x4;

#define MFMA16(a, b, c) __builtin_amdgcn_mfma_f32_16x16x32_bf16((a), (b), (c), 0, 0, 0)

static __device__ __forceinline__ unsigned short f2bf(float x) {
  union { float f; unsigned int u; } v; v.f = x;
  unsigned int r = v.u + 0x7fffu + ((v.u >> 16) & 1u);   // RNE
  return (unsigned short)(r >> 16);
}

static __device__ __forceinline__ void gload_lds16(const void* g, void* l) {
  __builtin_amdgcn_global_load_lds(
      (__attribute__((address_space(1))) void*)(g),
      (__attribute__((address_space(3))) void*)(l), 16, 0, 0);
}

// ---------------- diagnostic fill (sentinels; f32 output) ----------------
__global__ void fill_kernel(float* p, int n, float v) {
  int i = blockIdx.x * blockDim.x + threadIdx.x;
  if (i < n) p[i] = v;
}

// ---------------- weight convert + transpose: Wt[n][k] = bf16(W[k][n]) ----------------
__global__ __launch_bounds__(256) void wtrans_kernel(
    const float* __restrict__ W0, const float* __restrict__ W1, const float* __restrict__ W2,
    unsigned short* __restrict__ T0, unsigned short* __restrict__ T1, unsigned short* __restrict__ T2)
{
  __shared__ __align__(16) float tile[64][65];
  const float* W = (blockIdx.z == 0) ? W0 : (blockIdx.z == 1) ? W1 : W2;
  unsigned short* T = (blockIdx.z == 0) ? T0 : (blockIdx.z == 1) ? T1 : T2;
  const int t = threadIdx.x;
  const int kb = blockIdx.x * 64, nb = blockIdx.y * 64;
  const int rr = t >> 4, cc = (t & 15) * 4;
#pragma unroll
  for (int p = 0; p < 4; ++p) {
    const int r = rr + p * 16;
    const f32x4 v = *(const f32x4*)&W[(size_t)(kb + r) * 1024 + nb + cc];
#pragma unroll
    for (int j = 0; j < 4; ++j) tile[r][cc + j] = v[j];
  }
  __syncthreads();
#pragma unroll
  for (int p = 0; p < 4; ++p) {
    const int n = rr + p * 16;
    u16x4 o;
#pragma unroll
    for (int j = 0; j < 4; ++j) o[j] = f2bf(tile[cc + j][n]);
    *(u16x4*)&T[(size_t)(nb + n) * 1024 + kb + cc] = o;
  }
}

// ---------------- projection GEMM: C[m][n] = sum_k A[m][k] * Wt[n][k] ----------------
// A: f32 [8192][1024] (converted to bf16 during staging). Bt: bf16 [1024][1024].
// mode 0: out[((b*16+h)*2048+s)*64+d]    (q/k layout, scale folded for q)
// mode 1: out[((b*16+h)*64+d)*2048+s]    (v transposed layout)
__global__ __launch_bounds__(256) void proj_gemm_kernel(
    const float* __restrict__ A, const unsigned short* __restrict__ Bt,
    unsigned short* __restrict__ outp, int mode, float scale)
{
  __shared__ __align__(16) unsigned short Alds[128 * 32];
  __shared__ __align__(16) unsigned short Blds[128 * 32];
  const int t = threadIdx.x;
  const int lane = t & 63, w = t >> 6;
  const int wr = w >> 1, wc = w & 1;
  const int m0 = blockIdx.y * 128, n0 = blockIdx.x * 128;

  f32x4 acc[4][4] = {};
  const int ar = t >> 1, ac = (t & 1) * 16;
  const float* aptr = A + (size_t)(m0 + ar) * 1024 + ac;

  for (int kt = 0; kt < 1024; kt += 32) {
    // stage A: 16 f32 -> 16 bf16 -> 2x ds_write_b128
    const f32x4 a0 = *(const f32x4*)(aptr + kt);
    const f32x4 a1 = *(const f32x4*)(aptr + kt + 4);
    const f32x4 a2 = *(const f32x4*)(aptr + kt + 8);
    const f32x4 a3 = *(const f32x4*)(aptr + kt + 12);
    bf16x8 p0, p1;
#pragma unroll
    for (int u = 0; u < 4; ++u) {
      p0[u]     = (short)f2bf(a0[u]);
      p0[u + 4] = (short)f2bf(a1[u]);
      p1[u]     = (short)f2bf(a2[u]);
      p1[u + 4] = (short)f2bf(a3[u]);
    }
    *(bf16x8*)&Alds[ar * 32 + ac]     = p0;
    *(bf16x8*)&Alds[ar * 32 + ac + 8] = p1;
    // stage B: direct global->LDS, 16B per lane (m97 pattern: linear src, linear dst)
#pragma unroll
    for (int i = 0; i < 2; ++i) {
      const int e = (t + i * 256) * 8;
      const int n = e >> 5, kk = e & 31;
      gload_lds16(&Bt[(size_t)(n0 + n) * 1024 + kt + kk], &Blds[e]);
    }
    __syncthreads();

    bf16x8 af[4], bfv[4];
#pragma unroll
    for (int m = 0; m < 4; ++m)
      af[m] = *(const bf16x8*)&Alds[(wr * 64 + m * 16 + (lane & 15)) * 32 + (lane >> 4) * 8];
#pragma unroll
    for (int n = 0; n < 4; ++n)
      bfv[n] = *(const bf16x8*)&Blds[(wc * 64 + n * 16 + (lane & 15)) * 32 + (lane >> 4) * 8];
#pragma unroll
    for (int m = 0; m < 4; ++m)
#pragma unroll
      for (int n = 0; n < 4; ++n)
        acc[m][n] = MFMA16(af[m], bfv[n], acc[m][n]);
    __syncthreads();
  }

  // epilogue: C/D layout col=lane&15, row=(lane>>4)*4+reg  [m89]
#pragma unroll
  for (int mi = 0; mi < 4; ++mi) {
#pragma unroll
    for (int ni = 0; ni < 4; ++ni) {
      const int nn = n0 + wc * 64 + ni * 16 + (lane & 15);
      const int h = nn >> 6, d = nn & 63;
      const int mbase = m0 + wr * 64 + mi * 16 + ((lane >> 4) << 2);
      const int b = mbase >> 11;
      const int s = mbase & 2047;
      if (mode == 0) {
#pragma unroll
        for (int j = 0; j < 4; ++j)
          outp[((size_t)(b * 16 + h) * 2048 + (s + j)) * 64 + d] = f2bf(acc[mi][ni][j] * scale);
      } else {
        u16x4 o;
#pragma unroll
        for (int j = 0; j < 4; ++j) o[j] = f2bf(acc[mi][ni][j] * scale);
        *(u16x4*)&outp[((size_t)(b * 16 + h) * 64 + d) * 2048 + s] = o;
      }
    }
  }
}

// ---------------- flash attention ----------------
// qa/ka: bf16 [BH][2048][64] (q pre-scaled by 1/8). va: bf16 [BH][64][2048].
// out: f32 [B][2048][1024]. One block = one (b,h) x 64 q-rows; 4 waves x 16 rows.
__global__ __launch_bounds__(256) void attn_kernel(
    const unsigned short* __restrict__ qa, const unsigned short* __restrict__ ka,
    const unsigned short* __restrict__ va, const int* __restrict__ Qlen,
    const int* __restrict__ Vlen, float* __restrict__ outp)
{
  __shared__ __align__(16) unsigned short Klds[64 * 64];   // [kpos][d], XOR-swizzled
  __shared__ __align__(16) unsigned short Vlds[64 * 64];   // [d][kpos], XOR-swizzled
  __shared__ __align__(16) unsigned short Plds[4][16 * 64];
  const int t = threadIdx.x, lane = t & 63, w = t >> 6;
  const int bh = blockIdx.y, b = bh >> 4, h = bh & 15;
  const int q0 = blockIdx.x * 64;
  const int Lq = Qlen[b], Lv = Vlen[b];
  float* outb = outp + (size_t)b * 2048 * 1024 + h * 64;

  if (q0 >= Lq) {  // entire q-tile masked: zero our 64x64 f32 slab
    const int r = t >> 2, c0 = (t & 3) * 16;
    const f32x4 z = {0.f, 0.f, 0.f, 0.f};
#pragma unroll
    for (int j = 0; j < 4; ++j)
      *(f32x4*)&outb[(size_t)(q0 + r) * 1024 + c0 + j * 4] = z;
    return;
  }

  const unsigned short* qb = qa + (size_t)bh * 2048 * 64;
  const unsigned short* kb = ka + (size_t)bh * 2048 * 64;
  const unsigned short* vb = va + (size_t)bh * 64 * 2048;

  // Q A-fragments in registers (row = lane&15, k = (lane>>4)*8, 2 halves of Dh=64)
  bf16x8 aq[2];
  {
    const int qrow = q0 + w * 16 + (lane & 15);
#pragma unroll
    for (int f = 0; f < 2; ++f)
      aq[f] = *(const bf16x8*)&qb[(size_t)qrow * 64 + (lane >> 4) * 8 + f * 32];
  }

  float m_run[4], l_run[4];
  f32x4 acc_o[4] = {};
#pragma unroll
  for (int j = 0; j < 4; ++j) { m_run[j] = -3.0e38f; l_run[j] = 0.0f; }

  const int nt = (Lv + 63) >> 6;
  for (int kt = 0; kt < nt; ++kt) {
    const int k0 = kt * 64;
    // reg-staged K/V with software XOR swizzle: Klds[r][x] = K[k0+r][x ^ ((r&7)*8)]
#pragma unroll
    for (int i = 0; i < 2; ++i) {
      const int cidx = t + i * 256;          // 512 chunks of 8 elements
      const int r = cidx >> 3, c8 = cidx & 7;
      const int dst = r * 64 + ((c8 ^ (r & 7)) * 8);
      const bf16x8 kv = *(const bf16x8*)&kb[(size_t)(k0 + r) * 64 + c8 * 8];
      const bf16x8 vv = *(const bf16x8*)&vb[(size_t)r * 2048 + k0 + c8 * 8];
      *(bf16x8*)&Klds[dst] = kv;
      *(bf16x8*)&Vlds[dst] = vv;
    }
    __syncthreads();

    // QK^T: S-tile 16q x 64k per wave; B-frag rows = kpos (output col), swizzled read
    f32x4 s4[4];
#pragma unroll
    for (int kbk = 0; kbk < 4; ++kbk) {
      const int row = kbk * 16 + (lane & 15);
      f32x4 acc = {0.f, 0.f, 0.f, 0.f};
#pragma unroll
      for (int ds = 0; ds < 2; ++ds) {
        const int col = (((lane >> 4) * 8) + ds * 32) ^ ((row & 7) << 3);
        const bf16x8 bk = *(const bf16x8*)&Klds[row * 64 + col];
        acc = MFMA16(aq[ds], bk, acc);
      }
      if (k0 + row >= Lv) {   // V_len mask (output col = lane&15-indexed kpos)
#pragma unroll
        for (int j = 0; j < 4; ++j) acc[j] = -1e30f;
      }
      s4[kbk] = acc;
    }

    // online softmax: rowmax over 4 blocks + 16-lane butterfly (reduce over cols)
    f32x4 rm;
#pragma unroll
    for (int j = 0; j < 4; ++j)
      rm[j] = fmaxf(fmaxf(s4[0][j], s4[1][j]), fmaxf(s4[2][j], s4[3][j]));
#pragma unroll
    for (int msk = 1; msk <= 8; msk <<= 1)
#pragma unroll
      for (int j = 0; j < 4; ++j)
        rm[j] = fmaxf(rm[j], __shfl_xor(rm[j], msk));

    float mn[4], esc[4];
#pragma unroll
    for (int j = 0; j < 4; ++j) {
      mn[j] = fmaxf(m_run[j], rm[j]);
      esc[j] = __expf(m_run[j] - mn[j]);
      m_run[j] = mn[j];
    }

    float p[4][4];
    f32x4 rs = {0.f, 0.f, 0.f, 0.f};
#pragma unroll
    for (int kbk = 0; kbk < 4; ++kbk)
#pragma unroll
      for (int j = 0; j < 4; ++j) {
        p[kbk][j] = __expf(s4[kbk][j] - mn[j]);
        rs[j] += p[kbk][j];
      }
#pragma unroll
    for (int msk = 1; msk <= 8; msk <<= 1)
#pragma unroll
      for (int j = 0; j < 4; ++j)
        rs[j] += __shfl_xor(rs[j], msk);
#pragma unroll
    for (int j = 0; j < 4; ++j) l_run[j] = l_run[j] * esc[j] + rs[j];
#pragma unroll
    for (int d = 0; d < 4; ++d)
#pragma unroll
      for (int j = 0; j < 4; ++j) acc_o[d][j] *= esc[j];

    // P (C-layout) -> LDS (swizzled) -> A-fragments; per-wave private buffer
    unsigned short* pl = &Plds[w][0];
#pragma unroll
    for (int kbk = 0; kbk < 4; ++kbk)
#pragma unroll
      for (int j = 0; j < 4; ++j) {
        const int row = (lane >> 4) * 4 + j;
        const int col = (kbk * 16 + (lane & 15)) ^ ((row & 7) << 3);
        pl[row * 64 + col] = f2bf(p[kbk][j]);
      }
    bf16x8 pf[2];
#pragma unroll
    for (int ks = 0; ks < 2; ++ks) {
      const int row = lane & 15;
      const int col = ((lane >> 4) * 8 + ks * 32) ^ ((row & 7) << 3);
      pf[ks] = *(const bf16x8*)&pl[row * 64 + col];
    }

    // PV: O[16q][64d] += P * V; V B-frag from v_t layout (k-contiguous)
#pragma unroll
    for (int db = 0; db < 4; ++db) {
#pragma unroll
      for (int ks = 0; ks < 2; ++ks) {
        const int vrow = db * 16 + (lane & 15);
        const int vcol = ((lane >> 4) * 8 + ks * 32) ^ ((vrow & 7) << 3);
        const bf16x8 vf = *(const bf16x8*)&Vlds[vrow * 64 + vcol];
        acc_o[db] = MFMA16(pf[ks], vf, acc_o[db]);
      }
    }
    __syncthreads();
  }

  // epilogue: normalize, Q_len mask, write f32
#pragma unroll
  for (int j = 0; j < 4; ++j) {
    const int row = q0 + w * 16 + (lane >> 4) * 4 + j;
    const float rl = 1.0f / l_run[j];
#pragma unroll
    for (int db = 0; db < 4; ++db) {
      const float v = acc_o[db][j] * rl;
      outb[(size_t)row * 1024 + db * 16 + (lane & 15)] = (row < Lq) ? v : 0.0f;
    }
  }
}

extern "C" void kernel_launch(void* const* d_in, const int* in_sizes, int n_in,
                              void* d_out, int out_size, void* d_ws, size_t ws_size,
                              hipStream_t stream) {
  float* out = (float*)d_out;

  // SENTINEL 2: verify documented input ordering via in_sizes. Mismatch -> 512.0 fill.
  const int expect[8] = {8388608, 8388608, 8388608, 1048576, 1048576, 1048576, 4, 4};
  bool order_ok = (n_in == 8);
  if (order_ok)
    for (int i = 0; i < 8; ++i) order_ok = order_ok && (in_sizes[i] == expect[i]);
  if (!order_ok) {
    fill_kernel<<<(out_size + 255) / 256, 256, 0, stream>>>(out, out_size, 512.0f);
    return;
  }

  // SENTINEL 1: workspace needs 3x 1M + 3x 8M bf16 elements (54.5 MB). Too small -> 256.0 fill.
  const size_t need = ((size_t)3 * 1024 * 1024 + (size_t)3 * 8192 * 1024) * 2;
  if (ws_size < need) {
    fill_kernel<<<(out_size + 255) / 256, 256, 0, stream>>>(out, out_size, 256.0f);
    return;
  }

  const float* Qs = (const float*)d_in[0];
  const float* Ks = (const float*)d_in[1];
  const float* Vs = (const float*)d_in[2];
  const float* WQ = (const float*)d_in[3];
  const float* WK = (const float*)d_in[4];
  const float* WV = (const float*)d_in[5];
  const int* Qlen = (const int*)d_in[6];
  const int* Vlen = (const int*)d_in[7];

  unsigned short* WQt = (unsigned short*)d_ws;
  unsigned short* WKt = WQt + (size_t)1024 * 1024;
  unsigned short* WVt = WKt + (size_t)1024 * 1024;
  unsigned short* qa  = WVt + (size_t)1024 * 1024;
  unsigned short* ka  = qa + (size_t)8192 * 1024;
  unsigned short* va  = ka + (size_t)8192 * 1024;

  wtrans_kernel<<<dim3(16, 16, 3), 256, 0, stream>>>(WQ, WK, WV, WQt, WKt, WVt);
  proj_gemm_kernel<<<dim3(8, 64), 256, 0, stream>>>(Qs, WQt, qa, 0, 0.125f);  // fold 1/sqrt(64)
  proj_gemm_kernel<<<dim3(8, 64), 256, 0, stream>>>(Ks, WKt, ka, 0, 1.0f);
  proj_gemm_kernel<<<dim3(8, 64), 256, 0, stream>>>(Vs, WVt, va, 1, 1.0f);    // transposed out
  attn_kernel<<<dim3(32, 64), 256, 0, stream>>>(qa, ka, va, Qlen, Vlen, out);
}